// Round 6
// baseline (256.709 us; speedup 1.0000x reference)
//
#include <hip/hip_runtime.h>
#include <hip/hip_bf16.h>
#include <cstdint>

typedef __bf16 bf16;
typedef __bf16 bf16x8 __attribute__((ext_vector_type(8)));
typedef float f32x4 __attribute__((ext_vector_type(4)));

#define MFMA16(A, B, C) __builtin_amdgcn_mfma_f32_16x16x32_bf16((A), (B), (C), 0, 0, 0)

// async global->LDS 16B DMA; LDS dest must be wave-uniform base + lane*16
__device__ __forceinline__ void async16(const bf16* g, bf16* l) {
    __builtin_amdgcn_global_load_lds(
        (const __attribute__((address_space(1))) void*)g,
        (__attribute__((address_space(3))) void*)l, 16, 0, 0);
}

// ---------------------------------------------------------------------------
// fused f32 -> bf16 convert for all three inputs (one launch)
// ---------------------------------------------------------------------------
__global__ void cvt_all(const float* __restrict__ x, const float* __restrict__ wq,
                        const float* __restrict__ wo, bf16* __restrict__ xb,
                        bf16* __restrict__ wqb, bf16* __restrict__ wob) {
    const int bid = blockIdx.x;
    const float* s;
    bf16* d;
    int off;
    if (bid < 4096)      { s = x;  d = xb;  off = bid; }
    else if (bid < 5632) { s = wq; d = wqb; off = bid - 4096; }
    else                 { s = wo; d = wob; off = bid - 5632; }
    const size_t i = ((size_t)off * 256 + threadIdx.x) * 8;
    const float4 a = *(const float4*)(s + i);
    const float4 b2 = *(const float4*)(s + i + 4);
    bf16x8 r;
    r[0] = (bf16)a.x; r[1] = (bf16)a.y; r[2] = (bf16)a.z; r[3] = (bf16)a.w;
    r[4] = (bf16)b2.x; r[5] = (bf16)b2.y; r[6] = (bf16)b2.z; r[7] = (bf16)b2.w;
    *(bf16x8*)(d + i) = r;
}

// ---------------------------------------------------------------------------
// 8-phase 256x256 NT GEMM, faithful m201-template port.
// BK=64, 512 thr (8 waves 2m x 4n), per-wave 128x64 out (8x4 accs).
// 4 phases/K-tile (quadrant mh x nh, 16 MFMA each), TWO barriers per phase.
// LDS 128 KiB: [buf][half][128 rows][8 chunks][8 elems] for A and B; each
// half-tile = 16 KiB = 2 async16/thread. Swizzle chunk ^= row&7 (R3 scheme,
// measured 0 conflicts): linear DMA dest + inverse-swizzled global source +
// swizzled ds_read. Stages for K-tile kt+2 issued at p1 (B) / p3 (A) of kt
// (released regions), 5-7 phases before consumption. Single counted gate per
// K-tile: vmcnt(8); s_barrier at the p3->p0 boundary (8 = newest stages).
// QKV scatter epilogue (O0=Q, O1=K, O2=V in (B,H,T,64)).
// ---------------------------------------------------------------------------
__launch_bounds__(512, 2)
__global__ void gemm8p(const bf16* __restrict__ A, const bf16* __restrict__ Bm,
                       bf16* __restrict__ O0, bf16* __restrict__ O1,
                       bf16* __restrict__ O2, int N, int K) {
    __shared__ alignas(16) bf16 As[2 * 2 * 8192];   // 64 KiB
    __shared__ alignas(16) bf16 Bs[2 * 2 * 8192];   // 64 KiB

    const int t = threadIdx.x, w = t >> 6, l = t & 63;
    const int quad = l >> 4, l15 = l & 15;
    const int wm = w >> 2, wn = w & 3;
    const int bh2 = wn >> 1;

    // XCD-aware bijective swizzle (nwg = 384, %8==0)
    const int nwg = (int)gridDim.x;
    const int wg = ((int)blockIdx.x & 7) * (nwg >> 3) + ((int)blockIdx.x >> 3);
    const int NBN = N >> 8;
    const int m0 = (wg / NBN) * 256, n0 = (wg % NBN) * 256;

    const int NT = K >> 6;

    // ---- stage constants: load j of a half-tile: id = j*512+t ----
    // row = id>>3 (128 rows/half), c = id&7; global chunk = c ^ (row&7)
    int a_src[2], b_src[2], sdst[2];
#pragma unroll
    for (int j = 0; j < 2; j++) {
        const int id = j * 512 + t;
        const int row = id >> 3, c = id & 7;
        const int gco = (c ^ (row & 7)) << 3;
        a_src[j] = (m0 + row) * K + gco;
        b_src[j] = (n0 + row) * K + gco;
        sdst[j] = id << 3;
    }

#define STAGE_A(kt_, buf, h)                                                  \
    do {                                                                      \
        async16(A + a_src[0] + (h) * 128 * K + (kt_) * 64,                    \
                &As[(((buf) * 2 + (h)) << 13) + sdst[0]]);                    \
        async16(A + a_src[1] + (h) * 128 * K + (kt_) * 64,                    \
                &As[(((buf) * 2 + (h)) << 13) + sdst[1]]);                    \
    } while (0)
#define STAGE_B(kt_, buf, h)                                                  \
    do {                                                                      \
        async16(Bm + b_src[0] + (h) * 128 * K + (kt_) * 64,                   \
                &Bs[(((buf) * 2 + (h)) << 13) + sdst[0]]);                    \
        async16(Bm + b_src[1] + (h) * 128 * K + (kt_) * 64,                   \
                &Bs[(((buf) * 2 + (h)) << 13) + sdst[1]]);                    \
    } while (0)

    // ---- read constants (swizzled chunk per k-half) ----
    const int sw = l15 & 7;
    const int pcs0 = (quad ^ sw) << 3;
    const int pcs1 = ((4 + quad) ^ sw) << 3;

    f32x4 acc[8][4] = {};

    // prologue: tiles 0 and 1, consumption order [B, A] per tile
    STAGE_B(0, 0, 0); STAGE_B(0, 0, 1);
    STAGE_A(0, 0, 0); STAGE_A(0, 0, 1);
    STAGE_B(1, 1, 0); STAGE_B(1, 1, 1);
    STAGE_A(1, 1, 0); STAGE_A(1, 1, 1);
    asm volatile("s_waitcnt vmcnt(8)" ::: "memory");  // tile 0 landed
    __builtin_amdgcn_s_barrier();

    for (int kt = 0; kt < NT; ++kt) {
        const int cb = kt & 1;
        const int kn = kt + 2;
        const bool st = (kn < NT);
        const int ab = ((cb * 2 + wm) << 13);
        const int bb = ((cb * 2 + bh2) << 13);
        const int brow = ((wn & 1) << 6) + l15;

        bf16x8 af[4][2], bfr[4][2];

        // ---- p0: read af(mh0) + all bf; MFMA quadrant (mh0, nh0) ----
#pragma unroll
        for (int mf = 0; mf < 4; mf++) {
            const int ro = ab + ((mf * 16 + l15) << 6);
            af[mf][0] = *(const bf16x8*)&As[ro + pcs0];
            af[mf][1] = *(const bf16x8*)&As[ro + pcs1];
        }
#pragma unroll
        for (int nf = 0; nf < 4; nf++) {
            const int ro = bb + ((brow + nf * 16) << 6);
            bfr[nf][0] = *(const bf16x8*)&Bs[ro + pcs0];
            bfr[nf][1] = *(const bf16x8*)&Bs[ro + pcs1];
        }
        asm volatile("" ::: "memory");
        __builtin_amdgcn_s_barrier();
        __builtin_amdgcn_s_setprio(1);
#pragma unroll
        for (int mf = 0; mf < 4; mf++)
#pragma unroll
            for (int nf = 0; nf < 2; nf++) {
                acc[mf][nf] = MFMA16(af[mf][0], bfr[nf][0], acc[mf][nf]);
                acc[mf][nf] = MFMA16(af[mf][1], bfr[nf][1], acc[mf][nf]);
            }
        __builtin_amdgcn_s_setprio(0);
        __builtin_amdgcn_s_barrier();

        // ---- p1: stage B(kt+2) into released B region; MFMA (mh0, nh1) ----
        if (st) { STAGE_B(kn, cb, 0); STAGE_B(kn, cb, 1); }
        asm volatile("" ::: "memory");
        __builtin_amdgcn_s_barrier();
        __builtin_amdgcn_s_setprio(1);
#pragma unroll
        for (int mf = 0; mf < 4; mf++)
#pragma unroll
            for (int nf = 0; nf < 2; nf++) {
                acc[mf][2 + nf] = MFMA16(af[mf][0], bfr[2 + nf][0], acc[mf][2 + nf]);
                acc[mf][2 + nf] = MFMA16(af[mf][1], bfr[2 + nf][1], acc[mf][2 + nf]);
            }
        __builtin_amdgcn_s_setprio(0);
        __builtin_amdgcn_s_barrier();

        // ---- p2: read af(mh1); MFMA (mh1, nh0) ----
#pragma unroll
        for (int mf = 0; mf < 4; mf++) {
            const int ro = ab + (((4 + mf) * 16 + l15) << 6);
            af[mf][0] = *(const bf16x8*)&As[ro + pcs0];
            af[mf][1] = *(const bf16x8*)&As[ro + pcs1];
        }
        asm volatile("" ::: "memory");
        __builtin_amdgcn_s_barrier();
        __builtin_amdgcn_s_setprio(1);
#pragma unroll
        for (int mf = 0; mf < 4; mf++)
#pragma unroll
            for (int nf = 0; nf < 2; nf++) {
                acc[4 + mf][nf] = MFMA16(af[mf][0], bfr[nf][0], acc[4 + mf][nf]);
                acc[4 + mf][nf] = MFMA16(af[mf][1], bfr[nf][1], acc[4 + mf][nf]);
            }
        __builtin_amdgcn_s_setprio(0);
        __builtin_amdgcn_s_barrier();

        // ---- p3: stage A(kt+2); MFMA (mh1, nh1); counted gate + barrier ----
        if (st) { STAGE_A(kn, cb, 0); STAGE_A(kn, cb, 1); }
        asm volatile("" ::: "memory");
        __builtin_amdgcn_s_barrier();
        __builtin_amdgcn_s_setprio(1);
#pragma unroll
        for (int mf = 0; mf < 4; mf++)
#pragma unroll
            for (int nf = 0; nf < 2; nf++) {
                acc[4 + mf][2 + nf] = MFMA16(af[mf][0], bfr[2 + nf][0], acc[4 + mf][2 + nf]);
                acc[4 + mf][2 + nf] = MFMA16(af[mf][1], bfr[2 + nf][1], acc[4 + mf][2 + nf]);
            }
        __builtin_amdgcn_s_setprio(0);
        // gate for next tile: everything except the 8 newest stages drained
        if (st) asm volatile("s_waitcnt vmcnt(8)" ::: "memory");
        else    asm volatile("s_waitcnt vmcnt(0)" ::: "memory");
        __builtin_amdgcn_s_barrier();
    }

    // ---- QKV scatter epilogue ----
#pragma unroll
    for (int nf = 0; nf < 4; nf++) {
        const int n = n0 + wn * 64 + nf * 16;
        const int sel = n >> 10;
        const int c = n & 1023;
        const int h = c >> 6;
        const int dd = c & 63;
        bf16* dst = (sel == 0) ? O0 : ((sel == 1) ? O1 : O2);
#pragma unroll
        for (int mf = 0; mf < 8; mf++) {
#pragma unroll
            for (int r = 0; r < 4; r++) {
                const int m = m0 + wm * 128 + mf * 16 + quad * 4 + r;
                const int b = m >> 11, tt = m & 2047;
                dst[((size_t)(b * 16 + h) * 2048 + tt) * 64 + dd + l15] =
                    (bf16)acc[mf][nf][r];
            }
        }
    }
#undef STAGE_A
#undef STAGE_B
}

// ---------------------------------------------------------------------------
// NT GEMM, m97 structure (known-good): used for the W_o projection.
// MODE 1: plain row-major f32 store to O0 (ld = N)
// ---------------------------------------------------------------------------
template <int MODE>
__launch_bounds__(256, 3)
__global__ void gemm_nt(const bf16* __restrict__ A, const bf16* __restrict__ Bm,
                        void* __restrict__ O0, bf16* __restrict__ O1,
                        bf16* __restrict__ O2, int N, int K) {
    __shared__ alignas(16) bf16 As[128 * 64];
    __shared__ alignas(16) bf16 Bs[128 * 64];

    const int t = threadIdx.x;
    const int w = t >> 6, l = t & 63, quad = l >> 4, l15 = l & 15;
    const int wm = w & 1, wn = w >> 1;

    const int gx = (int)gridDim.x;
    const int nwg = gx * (int)gridDim.y;
    const int wg0 = (int)blockIdx.y * gx + (int)blockIdx.x;
    const int wg = (wg0 & 7) * (nwg >> 3) + (wg0 >> 3);
    const int m0 = (wg / gx) * 128, n0 = (wg % gx) * 128;

    f32x4 acc[4][4] = {};

    const int srow = t >> 3, sch = t & 7;
    const bf16* ga = A + (size_t)(m0 + srow) * K + sch * 8;
    const bf16* gb = Bm + (size_t)(n0 + srow) * K + sch * 8;

    for (int kt = 0; kt < K; kt += 64) {
        __syncthreads();
#pragma unroll
        for (int i = 0; i < 4; i++) {
            async16(ga + (size_t)i * 32 * K + kt, &As[(i * 256 + t) * 8]);
            async16(gb + (size_t)i * 32 * K + kt, &Bs[(i * 256 + t) * 8]);
        }
        __syncthreads();

#pragma unroll
        for (int s = 0; s < 2; s++) {
            bf16x8 af[4], bfr[4];
#pragma unroll
            for (int im = 0; im < 4; im++)
                af[im] = *(const bf16x8*)&As[(wm * 64 + im * 16 + l15) * 64 + s * 32 + quad * 8];
#pragma unroll
            for (int in = 0; in < 4; in++)
                bfr[in] = *(const bf16x8*)&Bs[(wn * 64 + in * 16 + l15) * 64 + s * 32 + quad * 8];
#pragma unroll
            for (int im = 0; im < 4; im++)
#pragma unroll
                for (int in = 0; in < 4; in++)
                    acc[im][in] = MFMA16(af[im], bfr[in], acc[im][in]);
        }
    }

    if (MODE == 0) {
        bf16* Q0 = (bf16*)O0;
#pragma unroll
        for (int in = 0; in < 4; in++) {
            const int n = n0 + wn * 64 + in * 16;
            const int sel = n >> 10;
            const int c = n & 1023;
            const int h = c >> 6;
            const int dd = c & 63;
            bf16* dst = (sel == 0) ? Q0 : ((sel == 1) ? O1 : O2);
#pragma unroll
            for (int im = 0; im < 4; im++) {
#pragma unroll
                for (int r = 0; r < 4; r++) {
                    const int m = m0 + wm * 64 + im * 16 + quad * 4 + r;
                    const int b = m >> 11, tt = m & 2047;
                    dst[((size_t)(b * 16 + h) * 2048 + tt) * 64 + dd + l15] =
                        (bf16)acc[im][in][r];
                }
            }
        }
    } else {
        float* Of = (float*)O0;
#pragma unroll
        for (int im = 0; im < 4; im++) {
#pragma unroll
            for (int in = 0; in < 4; in++) {
#pragma unroll
                for (int r = 0; r < 4; r++) {
                    const int m = m0 + wm * 64 + im * 16 + quad * 4 + r;
                    const int n = n0 + wn * 64 + in * 16 + l15;
                    Of[(size_t)m * N + n] = acc[im][in][r];
                }
            }
        }
    }
}

// ---------------------------------------------------------------------------
// V transpose: V (bh, T, 64) -> Vt (bh, 64, T). 64x64 tiles via LDS.
// ---------------------------------------------------------------------------
__launch_bounds__(256, 4)
__global__ void vtrans(const bf16* __restrict__ V, bf16* __restrict__ Vt) {
    __shared__ alignas(16) bf16 Ls[64 * 72];
    const int t = threadIdx.x, bh = blockIdx.y, tt = blockIdx.x;
#pragma unroll
    for (int i = 0; i < 2; i++) {
        const int id = i * 256 + t, r = id >> 3, c = id & 7;
        *(bf16x8*)&Ls[r * 72 + c * 8] =
            *(const bf16x8*)&V[((size_t)bh * 2048 + tt * 64 + r) * 64 + c * 8];
    }
    __syncthreads();
#pragma unroll
    for (int i = 0; i < 2; i++) {
        const int id = i * 256 + t, d = id >> 3, c = id & 7;
        bf16x8 v;
#pragma unroll
        for (int j = 0; j < 8; j++) v[j] = Ls[(c * 8 + j) * 72 + d];
        *(bf16x8*)&Vt[((size_t)bh * 64 + d) * 2048 + tt * 64 + c * 8] = v;
    }
}

// ---------------------------------------------------------------------------
// Causal flash attention, merged-pair K-loop (see R5 notes). T14 async-STAGE:
// next tile's K/V loads issued before compute so HBM latency hides under MFMA.
// ---------------------------------------------------------------------------
__launch_bounds__(256, 4)
__global__ void attn_fwd(const bf16* __restrict__ Q, const bf16* __restrict__ Kk,
                         const bf16* __restrict__ Vt, bf16* __restrict__ O) {
    __shared__ alignas(16) bf16 Ks[64 * 72];      // K tile  [kpos][d], ld=72
    __shared__ alignas(16) bf16 Vs[64 * 72];      // Vt tile [d][kpos], ld=72

    const int t = threadIdx.x, w = t >> 6, l = t & 63;
    const int quad = l >> 4, l15 = l & 15;
    const int bh = blockIdx.y, pair = blockIdx.x;
    const int b = bh >> 4, h = bh & 15;
    const int sr = t >> 3, sc = t & 7;

    const bf16* Qbase = Q + (size_t)bh * 2048 * 64;
    const bf16* Kbase = Kk + (size_t)bh * 2048 * 64;
    const bf16* Vbase = Vt + (size_t)bh * 64 * 2048;

    const int qt0 = pair, qt1 = 31 - pair;

    int kr[4];
#pragma unroll
    for (int nt = 0; nt < 4; nt++)
        kr[nt] = (nt >> 1) * 32 + (l15 >> 2) * 8 + (nt & 1) * 4 + (l15 & 3);

    bf16x8 aq[2][2];
#pragma unroll
    for (int hf = 0; hf < 2; hf++) {
        const int qrow = (hf ? qt1 : qt0) * 64 + w * 16 + l15;
        aq[hf][0] = *(const bf16x8*)&Qbase[(size_t)qrow * 64 + quad * 8];
        aq[hf][1] = *(const bf16x8*)&Qbase[(size_t)qrow * 64 + 32 + quad * 8];
#pragma unroll
        for (int j = 0; j < 8; j++) {
            aq[hf][0][j] = aq[hf][0][j] * (bf16)0.1803369f;
            aq[hf][1][j] = aq[hf][1][j] * (bf16)0.1803369f;
        }
    }

    bf16x8 ones;
#pragma unroll
    for (int j = 0; j < 8; j++) ones[j] = (bf16)1.0f;

    f32x4 liacc[2] = {};
    f32x4 oa[2][4] = {};

    bf16x8 rk0 = *(const bf16x8*)&Kbase[(size_t)sr * 64 + sc * 8];
    bf16x8 rk1 = *(const bf16x8*)&Kbase[(size_t)(sr + 32) * 64 + sc * 8];
    bf16x8 rv0 = *(const bf16x8*)&Vbase[(size_t)sr * 2048 + sc * 8];
    bf16x8 rv1 = *(const bf16x8*)&Vbase[(size_t)(sr + 32) * 2048 + sc * 8];

    for (int kt = 0; kt <= qt1; kt++) {
        __syncthreads();
        *(bf16x8*)&Ks[sr * 72 + sc * 8] = rk0;
        *(bf16x8*)&Ks[(sr + 32) * 72 + sc * 8] = rk1;
        *(bf16x8*)&Vs[sr * 72 + sc * 8] = rv0;
        *(bf16x8*)&Vs[(sr + 32) * 72 + sc * 8] = rv1;
        __syncthreads();

        if (kt < qt1) {
            const int kn = kt + 1;
            rk0 = *(const bf16x8*)&Kbase[(size_t)(kn * 64 + sr) * 64 + sc * 8];
            rk1 = *(const bf16x8*)&Kbase[(size_t)(kn * 64 + sr + 32) * 64 + sc * 8];
            rv0 = *(const bf16x8*)&Vbase[(size_t)sr * 2048 + kn * 64 + sc * 8];
            rv1 = *(const bf16x8*)&Vbase[(size_t)(sr + 32) * 2048 + kn * 64 + sc * 8];
        }

        const bool do0 = (kt <= qt0);

        bf16x8 ap[2][2];
#pragma unroll
        for (int np = 0; np < 2; np++) {
            bf16x8 ka[2][2];
#pragma unroll
            for (int i = 0; i < 2; i++) {
                ka[i][0] = *(const bf16x8*)&Ks[kr[2 * np + i] * 72 + quad * 8];
                ka[i][1] = *(const bf16x8*)&Ks[kr[2 * np + i] * 72 + 32 + quad * 8];
            }
#pragma unroll
            for (int hf = 0; hf < 2; hf++) {
                if (hf == 0 && !do0) continue;
                const bool diag = (kt == (hf ? qt1 : qt0));
#pragma unroll
                for (int i = 0; i < 2; i++) {
                    f32x4 s = {};
                    s = MFMA16(ka[i][0], aq[hf][0], s);
                    s = MFMA16(ka[i][1], aq[hf][1], s);
                    const int kbase = np * 32 + quad * 8 + i * 4;
#pragma unroll
                    for (int r = 0; r < 4; r++) {
                        float x = s[r];
                        if (diag && (kbase + r) > (w * 16 + l15)) x = -1e30f;
                        ap[hf][np][i * 4 + r] = (bf16)__builtin_amdgcn_exp2f(x);
                    }
                }
            }
        }

#pragma unroll
        for (int s2 = 0; s2 < 2; s2++) {
            if (do0) liacc[0] = MFMA16(ap[0][s2], ones, liacc[0]);
            liacc[1] = MFMA16(ap[1][s2], ones, liacc[1]);
#pragma unroll
            for (int dt = 0; dt < 4; dt++) {
                bf16x8 bv = *(const bf16x8*)&Vs[(dt * 16 + l15) * 72 + s2 * 32 + quad * 8];
                if (do0) oa[0][dt] = MFMA16(ap[0][s2], bv, oa[0][dt]);
                oa[1][dt] = MFMA16(ap[1][s2], bv, oa[1][dt]);
            }
        }
    }

#pragma unroll
    for (int hf = 0; hf < 2; hf++) {
        const int qt = hf ? qt1 : qt0;
#pragma unroll
        for (int r = 0; r < 4; r++) {
            const float inv = __builtin_amdgcn_rcpf(liacc[hf][r]);
            const int m = b * 2048 + qt * 64 + w * 16 + quad * 4 + r;
#pragma unroll
            for (int dt = 0; dt < 4; dt++) {
                O[(size_t)m * 1024 + h * 64 + dt * 16 + l15] = (bf16)(oa[hf][dt][r] * inv);
            }
        }
    }
}

// ---------------------------------------------------------------------------
extern "C" void kernel_launch(void* const* d_in, const int* in_sizes, int n_in,
                              void* d_out, int out_size, void* d_ws, size_t ws_size,
                              hipStream_t stream) {
    const float* x = (const float*)d_in[0];     // (8192, 1024) f32
    const float* wqkv = (const float*)d_in[1];  // (3072, 1024) f32
    const float* wo = (const float*)d_in[2];    // (1024, 1024) f32

    const size_t SZ = (size_t)8192 * 1024;
    bf16* xb = (bf16*)d_ws;                 // x bf16; reused as Vt after QKV gemm
    bf16* wqb = xb + SZ;                    // W_qkv bf16
    bf16* wob = wqb + (size_t)3072 * 1024;  // W_o bf16
    bf16* Qw = wob + (size_t)1024 * 1024;
    bf16* Kw = Qw + SZ;
    bf16* Vw = Kw + SZ;                     // V, then reused as attn output
    bf16* Vtw = xb;                         // V transposed (xb dead by then)

    dim3 blk(256);
    cvt_all<<<6144, blk, 0, stream>>>(x, wqkv, wo, xb, wqb, wob);
    gemm8p<<<dim3(384), dim3(512), 0, stream>>>(xb, wqb, Qw, Kw, Vw, 3072, 1024);
    vtrans<<<dim3(32, 64), blk, 0, stream>>>(Vw, Vtw);
    attn_fwd<<<dim3(16, 64), blk, 0, stream>>>(Qw, Kw, Vtw, Vw);
    gemm_nt<1><<<dim3(8, 64), blk, 0, stream>>>(Vw, wob, d_out, nullptr, nullptr, 1024, 1024);
}

// Round 7
// 249.625 us; speedup vs baseline: 1.0284x; 1.0284x over previous
//
#include <hip/hip_runtime.h>
#include <hip/hip_bf16.h>
#include <cstdint>

typedef __bf16 bf16;
typedef __bf16 bf16x8 __attribute__((ext_vector_type(8)));
typedef float f32x4 __attribute__((ext_vector_type(4)));

#define MFMA16(A, B, C) __builtin_amdgcn_mfma_f32_16x16x32_bf16((A), (B), (C), 0, 0, 0)

// async global->LDS 16B DMA; LDS dest must be wave-uniform base + lane*16
__device__ __forceinline__ void async16(const bf16* g, bf16* l) {
    __builtin_amdgcn_global_load_lds(
        (const __attribute__((address_space(1))) void*)g,
        (__attribute__((address_space(3))) void*)l, 16, 0, 0);
}

// ---------------------------------------------------------------------------
// fused f32 -> bf16 convert for all three inputs (one launch)
// ---------------------------------------------------------------------------
__global__ void cvt_all(const float* __restrict__ x, const float* __restrict__ wq,
                        const float* __restrict__ wo, bf16* __restrict__ xb,
                        bf16* __restrict__ wqb, bf16* __restrict__ wob) {
    const int bid = blockIdx.x;
    const float* s;
    bf16* d;
    int off;
    if (bid < 4096)      { s = x;  d = xb;  off = bid; }
    else if (bid < 5632) { s = wq; d = wqb; off = bid - 4096; }
    else                 { s = wo; d = wob; off = bid - 5632; }
    const size_t i = ((size_t)off * 256 + threadIdx.x) * 8;
    const float4 a = *(const float4*)(s + i);
    const float4 b2 = *(const float4*)(s + i + 4);
    bf16x8 r;
    r[0] = (bf16)a.x; r[1] = (bf16)a.y; r[2] = (bf16)a.z; r[3] = (bf16)a.w;
    r[4] = (bf16)b2.x; r[5] = (bf16)b2.y; r[6] = (bf16)b2.z; r[7] = (bf16)b2.w;
    *(bf16x8*)(d + i) = r;
}

// ---------------------------------------------------------------------------
// NT GEMM, pure bf16, async global_load_lds staging (m97 structure, proven).
// 128x128 tile, BK=64, 256 threads (4 waves, 2x2 wave grid, 4x4 16x16 accs).
// MODE 0 (QKV): each block's n-range is purely Q, K, or V.
//   Q/K blocks: scatter epilogue to (B,H,T,64) bf16.
//   V blocks (n0>=2048): LDS-transpose epilogue writes Vt (B,H,64,T) bf16
//   directly (reuses the 32 KiB As/Bs LDS as a 128x128 transpose buffer,
//   XOR-swizzled rows so scalar writes and b128 reads stay ~2-way) ->
//   the standalone vtrans kernel is eliminated.
// MODE 1: plain row-major f32 store to O0 (ld = N)
// ---------------------------------------------------------------------------
template <int MODE>
__launch_bounds__(256, 3)
__global__ void gemm_nt(const bf16* __restrict__ A, const bf16* __restrict__ Bm,
                        void* __restrict__ O0, bf16* __restrict__ O1,
                        bf16* __restrict__ O2, int N, int K) {
    __shared__ alignas(16) bf16 SM[2][128 * 64];
    bf16* const As = SM[0];
    bf16* const Bs = SM[1];

    const int t = threadIdx.x;
    const int w = t >> 6, l = t & 63, quad = l >> 4, l15 = l & 15;
    const int wm = w & 1, wn = w >> 1;

    // XCD swizzle (nwg % 8 == 0 for both launches: 1536, 512)
    const int gx = (int)gridDim.x;
    const int nwg = gx * (int)gridDim.y;
    const int wg0 = (int)blockIdx.y * gx + (int)blockIdx.x;
    const int wg = (wg0 & 7) * (nwg >> 3) + (wg0 >> 3);
    const int m0 = (wg / gx) * 128, n0 = (wg % gx) * 128;

    f32x4 acc[4][4] = {};

    const int srow = t >> 3, sch = t & 7;
    const bf16* ga = A + (size_t)(m0 + srow) * K + sch * 8;
    const bf16* gb = Bm + (size_t)(n0 + srow) * K + sch * 8;

    for (int kt = 0; kt < K; kt += 64) {
        __syncthreads();
#pragma unroll
        for (int i = 0; i < 4; i++) {
            async16(ga + (size_t)i * 32 * K + kt, &As[(i * 256 + t) * 8]);
            async16(gb + (size_t)i * 32 * K + kt, &Bs[(i * 256 + t) * 8]);
        }
        __syncthreads();

#pragma unroll
        for (int s = 0; s < 2; s++) {
            bf16x8 af[4], bfr[4];
#pragma unroll
            for (int im = 0; im < 4; im++)
                af[im] = *(const bf16x8*)&As[(wm * 64 + im * 16 + l15) * 64 + s * 32 + quad * 8];
#pragma unroll
            for (int in = 0; in < 4; in++)
                bfr[in] = *(const bf16x8*)&Bs[(wn * 64 + in * 16 + l15) * 64 + s * 32 + quad * 8];
#pragma unroll
            for (int im = 0; im < 4; im++)
#pragma unroll
                for (int in = 0; in < 4; in++)
                    acc[im][in] = MFMA16(af[im], bfr[in], acc[im][in]);
        }
    }

    if (MODE == 0) {
        if (n0 >= 2048) {
            // ---- V block: transpose via LDS, write Vt (B,H,64,T) ----
            __syncthreads();  // main-loop LDS reads done
            bf16* const Ts = &SM[0][0];  // 128 cols x 128 rows (16384 elems)
            // write acc: phys elem = col*128 + (row ^ ((col&7)<<3))
#pragma unroll
            for (int in = 0; in < 4; in++) {
                const int col = wn * 64 + in * 16 + l15;
                const int cx = (col & 7) << 3;
#pragma unroll
                for (int im = 0; im < 4; im++) {
                    const int row0 = (wm * 64 + im * 16 + quad * 4) ^ cx;
#pragma unroll
                    for (int r = 0; r < 4; r++)
                        Ts[col * 128 + row0 + r] = (bf16)acc[im][in][r];
                }
            }
            __syncthreads();
            bf16* VtOut = O2;
            const int bb = m0 >> 11, tt0 = m0 & 2047;
            const int c0 = n0 - 2048;
#pragma unroll
            for (int p = 0; p < 8; p++) {
                const int col = p * 16 + w * 4 + (l >> 4);  // 0..127
                const int chunk = l & 15;                   // 8-row chunk
                const int physc = ((chunk ^ (col & 7)) & 7) + (chunk & 8);
                const bf16x8 v = *(const bf16x8*)&Ts[col * 128 + physc * 8];
                const int cg = c0 + col, h = cg >> 6, d = cg & 63;
                *(bf16x8*)&VtOut[((size_t)(bb * 16 + h) * 64 + d) * 2048 + tt0 + chunk * 8] = v;
            }
        } else {
            // ---- Q/K block: scatter epilogue ----
            bf16* Q0 = (bf16*)O0;
#pragma unroll
            for (int in = 0; in < 4; in++) {
                const int n = n0 + wn * 64 + in * 16;
                const int sel = n >> 10;
                const int c = n & 1023;
                const int h = c >> 6;
                const int dd = c & 63;
                bf16* dst = (sel == 0) ? Q0 : O1;
#pragma unroll
                for (int im = 0; im < 4; im++) {
#pragma unroll
                    for (int r = 0; r < 4; r++) {
                        const int m = m0 + wm * 64 + im * 16 + quad * 4 + r;
                        const int b = m >> 11, tt = m & 2047;
                        dst[((size_t)(b * 16 + h) * 2048 + tt) * 64 + dd + l15] =
                            (bf16)acc[im][in][r];
                    }
                }
            }
        }
    } else {
        float* Of = (float*)O0;
#pragma unroll
        for (int im = 0; im < 4; im++) {
#pragma unroll
            for (int in = 0; in < 4; in++) {
#pragma unroll
                for (int r = 0; r < 4; r++) {
                    const int m = m0 + wm * 64 + im * 16 + quad * 4 + r;
                    const int n = n0 + wn * 64 + in * 16 + l15;
                    Of[(size_t)m * N + n] = acc[im][in][r];
                }
            }
        }
    }
}

// ---------------------------------------------------------------------------
// Causal flash attention, merged-pair K-loop. Block p of (b,h) owns Q-tiles
// qt0=p, qt1=31-p and runs ONE kt-loop 0..qt1 (half0 active while kt<=qt0).
// S computed transposed (A=K w/ permuted row map, B=Q) so each lane's S^T
// regs are exactly the PV A-frags. No-reference softmax (2^c cancels); raw
// v_exp_f32; li row-sums ride the MFMA pipe (B = ones). Q pre-scaled.
// T14 async-STAGE: next tile's K/V loads issued before compute.
// Ks bank-conflict fix: physical chunk = (chunk + 2*(row>>3)) & 7 on both
// write and read (the read row-set kr collides 4-way mod 8 unswizzled;
// this swizzle enumerates to exactly 2-way = free).
// ---------------------------------------------------------------------------
__launch_bounds__(256, 4)
__global__ void attn_fwd(const bf16* __restrict__ Q, const bf16* __restrict__ Kk,
                         const bf16* __restrict__ Vt, bf16* __restrict__ O) {
    __shared__ alignas(16) bf16 Ks[64 * 72];      // K tile  [kpos][d], ld=72, swz
    __shared__ alignas(16) bf16 Vs[64 * 72];      // Vt tile [d][kpos], ld=72

    const int t = threadIdx.x, w = t >> 6, l = t & 63;
    const int quad = l >> 4, l15 = l & 15;
    const int bh = blockIdx.y, pair = blockIdx.x;
    const int b = bh >> 4, h = bh & 15;
    const int sr = t >> 3, sc = t & 7;

    const bf16* Qbase = Q + (size_t)bh * 2048 * 64;
    const bf16* Kbase = Kk + (size_t)bh * 2048 * 64;
    const bf16* Vbase = Vt + (size_t)bh * 64 * 2048;

    const int qt0 = pair, qt1 = 31 - pair;

    // permuted K-row map: tile nt, lane-m l15 -> local K row
    int kr[4], kchunk0[4], kchunk1[4];
#pragma unroll
    for (int nt = 0; nt < 4; nt++) {
        kr[nt] = (nt >> 1) * 32 + (l15 >> 2) * 8 + (nt & 1) * 4 + (l15 & 3);
        const int g2 = 2 * (kr[nt] >> 3);
        kchunk0[nt] = (quad + g2) & 7;
        kchunk1[nt] = (4 + quad + g2) & 7;
    }
    // Ks write chunk swizzle (same for rows sr and sr+32: +8 == 0 mod 8)
    const int scw = (sc + 2 * (sr >> 3)) & 7;

    // Q B-frags for both halves, pre-scaled by log2(e)/8
    bf16x8 aq[2][2];
#pragma unroll
    for (int hf = 0; hf < 2; hf++) {
        const int qrow = (hf ? qt1 : qt0) * 64 + w * 16 + l15;
        aq[hf][0] = *(const bf16x8*)&Qbase[(size_t)qrow * 64 + quad * 8];
        aq[hf][1] = *(const bf16x8*)&Qbase[(size_t)qrow * 64 + 32 + quad * 8];
#pragma unroll
        for (int j = 0; j < 8; j++) {
            aq[hf][0][j] = aq[hf][0][j] * (bf16)0.1803369f;
            aq[hf][1][j] = aq[hf][1][j] * (bf16)0.1803369f;
        }
    }

    bf16x8 ones;
#pragma unroll
    for (int j = 0; j < 8; j++) ones[j] = (bf16)1.0f;

    f32x4 liacc[2] = {};
    f32x4 oa[2][4] = {};

    // prologue: load tile 0 into registers
    bf16x8 rk0 = *(const bf16x8*)&Kbase[(size_t)sr * 64 + sc * 8];
    bf16x8 rk1 = *(const bf16x8*)&Kbase[(size_t)(sr + 32) * 64 + sc * 8];
    bf16x8 rv0 = *(const bf16x8*)&Vbase[(size_t)sr * 2048 + sc * 8];
    bf16x8 rv1 = *(const bf16x8*)&Vbase[(size_t)(sr + 32) * 2048 + sc * 8];

    for (int kt = 0; kt <= qt1; kt++) {
        __syncthreads();  // previous iter's tile reads done
        *(bf16x8*)&Ks[sr * 72 + scw * 8] = rk0;
        *(bf16x8*)&Ks[(sr + 32) * 72 + scw * 8] = rk1;
        *(bf16x8*)&Vs[sr * 72 + sc * 8] = rv0;
        *(bf16x8*)&Vs[(sr + 32) * 72 + sc * 8] = rv1;
        __syncthreads();

        // T14: issue next tile's loads now; latency hides under compute below
        if (kt < qt1) {
            const int kn = kt + 1;
            rk0 = *(const bf16x8*)&Kbase[(size_t)(kn * 64 + sr) * 64 + sc * 8];
            rk1 = *(const bf16x8*)&Kbase[(size_t)(kn * 64 + sr + 32) * 64 + sc * 8];
            rv0 = *(const bf16x8*)&Vbase[(size_t)sr * 2048 + kn * 64 + sc * 8];
            rv1 = *(const bf16x8*)&Vbase[(size_t)(sr + 32) * 2048 + kn * 64 + sc * 8];
        }

        const bool do0 = (kt <= qt0);

        // S^T by nt-pairs; ka frags shared across halves; pack PV A-frags
        bf16x8 ap[2][2];  // [hf][s2]
#pragma unroll
        for (int np = 0; np < 2; np++) {
            bf16x8 ka[2][2];
#pragma unroll
            for (int i = 0; i < 2; i++) {
                const int nt = 2 * np + i;
                ka[i][0] = *(const bf16x8*)&Ks[kr[nt] * 72 + kchunk0[nt] * 8];
                ka[i][1] = *(const bf16x8*)&Ks[kr[nt] * 72 + kchunk1[nt] * 8];
            }
#pragma unroll
            for (int hf = 0; hf < 2; hf++) {
                if (hf == 0 && !do0) continue;
                const bool diag = (kt == (hf ? qt1 : qt0));
#pragma unroll
                for (int i = 0; i < 2; i++) {
                    f32x4 s = {};
                    s = MFMA16(ka[i][0], aq[hf][0], s);
                    s = MFMA16(ka[i][1], aq[hf][1], s);
                    const int kbase = np * 32 + quad * 8 + i * 4;
#pragma unroll
                    for (int r = 0; r < 4; r++) {
                        float x = s[r];
                        if (diag && (kbase + r) > (w * 16 + l15)) x = -1e30f;
                        ap[hf][np][i * 4 + r] = (bf16)__builtin_amdgcn_exp2f(x);
                    }
                }
            }
        }

        // O += P V : bv frags read once, feed both halves.
#pragma unroll
        for (int s2 = 0; s2 < 2; s2++) {
            if (do0) liacc[0] = MFMA16(ap[0][s2], ones, liacc[0]);
            liacc[1] = MFMA16(ap[1][s2], ones, liacc[1]);
#pragma unroll
            for (int dt = 0; dt < 4; dt++) {
                bf16x8 bv = *(const bf16x8*)&Vs[(dt * 16 + l15) * 72 + s2 * 32 + quad * 8];
                if (do0) oa[0][dt] = MFMA16(ap[0][s2], bv, oa[0][dt]);
                oa[1][dt] = MFMA16(ap[1][s2], bv, oa[1][dt]);
            }
        }
    }

    // epilogue: liacc[hf][r] is already the full row-sum for q-row quad*4+r
#pragma unroll
    for (int hf = 0; hf < 2; hf++) {
        const int qt = hf ? qt1 : qt0;
#pragma unroll
        for (int r = 0; r < 4; r++) {
            const float inv = __builtin_amdgcn_rcpf(liacc[hf][r]);
            const int m = b * 2048 + qt * 64 + w * 16 + quad * 4 + r;
#pragma unroll
            for (int dt = 0; dt < 4; dt++) {
                O[(size_t)m * 1024 + h * 64 + dt * 16 + l15] = (bf16)(oa[hf][dt][r] * inv);
            }
        }
    }
}

// ---------------------------------------------------------------------------
extern "C" void kernel_launch(void* const* d_in, const int* in_sizes, int n_in,
                              void* d_out, int out_size, void* d_ws, size_t ws_size,
                              hipStream_t stream) {
    const float* x = (const float*)d_in[0];     // (8192, 1024) f32
    const float* wqkv = (const float*)d_in[1];  // (3072, 1024) f32
    const float* wo = (const float*)d_in[2];    // (1024, 1024) f32

    const size_t SZ = (size_t)8192 * 1024;
    bf16* xb = (bf16*)d_ws;                 // x bf16; reused as attn output
    bf16* wqb = xb + SZ;                    // W_qkv bf16
    bf16* wob = wqb + (size_t)3072 * 1024;  // W_o bf16
    bf16* Qw = wob + (size_t)1024 * 1024;
    bf16* Kw = Qw + SZ;
    bf16* Vtw = Kw + SZ;                    // Vt (B,H,64,T), written by gemm

    dim3 blk(256);
    cvt_all<<<6144, blk, 0, stream>>>(x, wqkv, wo, xb, wqb, wob);
    // writes Q/K scattered; V blocks write Vt directly (no vtrans kernel)
    gemm_nt<0><<<dim3(24, 64), blk, 0, stream>>>(xb, wqb, Qw, Kw, Vtw, 3072, 1024);
    // attn reads Vt, writes its output into xb (dead after the QKV gemm)
    attn_fwd<<<dim3(16, 64), blk, 0, stream>>>(Qw, Kw, Vtw, xb);
    gemm_nt<1><<<dim3(8, 64), blk, 0, stream>>>(xb, wob, d_out, nullptr, nullptr, 1024, 1024);
}

// Round 8
// 227.504 us; speedup vs baseline: 1.1284x; 1.0972x over previous
//
#include <hip/hip_runtime.h>
#include <hip/hip_bf16.h>
#include <cstdint>

typedef __bf16 bf16;
typedef __bf16 bf16x8 __attribute__((ext_vector_type(8)));
typedef float f32x4 __attribute__((ext_vector_type(4)));

#define MFMA16(A, B, C) __builtin_amdgcn_mfma_f32_16x16x32_bf16((A), (B), (C), 0, 0, 0)

// async global->LDS 16B DMA; LDS dest must be wave-uniform base + lane*16
__device__ __forceinline__ void async16(const bf16* g, bf16* l) {
    __builtin_amdgcn_global_load_lds(
        (const __attribute__((address_space(1))) void*)g,
        (__attribute__((address_space(3))) void*)l, 16, 0, 0);
}

// ---------------------------------------------------------------------------
// fused f32 -> bf16 convert for all three inputs (one launch)
// ---------------------------------------------------------------------------
__global__ void cvt_all(const float* __restrict__ x, const float* __restrict__ wq,
                        const float* __restrict__ wo, bf16* __restrict__ xb,
                        bf16* __restrict__ wqb, bf16* __restrict__ wob) {
    const int bid = blockIdx.x;
    const float* s;
    bf16* d;
    int off;
    if (bid < 4096)      { s = x;  d = xb;  off = bid; }
    else if (bid < 5632) { s = wq; d = wqb; off = bid - 4096; }
    else                 { s = wo; d = wob; off = bid - 5632; }
    const size_t i = ((size_t)off * 256 + threadIdx.x) * 8;
    const float4 a = *(const float4*)(s + i);
    const float4 b2 = *(const float4*)(s + i + 4);
    bf16x8 r;
    r[0] = (bf16)a.x; r[1] = (bf16)a.y; r[2] = (bf16)a.z; r[3] = (bf16)a.w;
    r[4] = (bf16)b2.x; r[5] = (bf16)b2.y; r[6] = (bf16)b2.z; r[7] = (bf16)b2.w;
    *(bf16x8*)(d + i) = r;
}

// ---------------------------------------------------------------------------
// NT GEMM, pure bf16, async global_load_lds staging (m97 structure, proven).
// 128x128 tile, BK=64, 256 threads (4 waves, 2x2 wave grid, 4x4 16x16 accs).
// MODE 0 (QKV): each block's n-range is purely Q, K, or V.
//   Q/K blocks: scatter epilogue to (B,H,T,64) bf16.
//   V blocks (n0>=2048): LDS-transpose epilogue writes Vt (B,H,64,T) bf16
//   directly (reuses the As/Bs LDS as a 128x128 transpose buffer,
//   XOR-swizzled rows) -> standalone vtrans kernel eliminated.
// MODE 1: plain row-major f32 store to O0 (ld = N)
// ---------------------------------------------------------------------------
template <int MODE>
__launch_bounds__(256, 3)
__global__ void gemm_nt(const bf16* __restrict__ A, const bf16* __restrict__ Bm,
                        void* __restrict__ O0, bf16* __restrict__ O1,
                        bf16* __restrict__ O2, int N, int K) {
    __shared__ alignas(16) bf16 SM[2][128 * 64];
    bf16* const As = SM[0];
    bf16* const Bs = SM[1];

    const int t = threadIdx.x;
    const int w = t >> 6, l = t & 63, quad = l >> 4, l15 = l & 15;
    const int wm = w & 1, wn = w >> 1;

    // XCD swizzle (nwg % 8 == 0 for both launches: 1536, 512)
    const int gx = (int)gridDim.x;
    const int nwg = gx * (int)gridDim.y;
    const int wg0 = (int)blockIdx.y * gx + (int)blockIdx.x;
    const int wg = (wg0 & 7) * (nwg >> 3) + (wg0 >> 3);
    const int m0 = (wg / gx) * 128, n0 = (wg % gx) * 128;

    f32x4 acc[4][4] = {};

    const int srow = t >> 3, sch = t & 7;
    const bf16* ga = A + (size_t)(m0 + srow) * K + sch * 8;
    const bf16* gb = Bm + (size_t)(n0 + srow) * K + sch * 8;

    for (int kt = 0; kt < K; kt += 64) {
        __syncthreads();
#pragma unroll
        for (int i = 0; i < 4; i++) {
            async16(ga + (size_t)i * 32 * K + kt, &As[(i * 256 + t) * 8]);
            async16(gb + (size_t)i * 32 * K + kt, &Bs[(i * 256 + t) * 8]);
        }
        __syncthreads();

#pragma unroll
        for (int s = 0; s < 2; s++) {
            bf16x8 af[4], bfr[4];
#pragma unroll
            for (int im = 0; im < 4; im++)
                af[im] = *(const bf16x8*)&As[(wm * 64 + im * 16 + l15) * 64 + s * 32 + quad * 8];
#pragma unroll
            for (int in = 0; in < 4; in++)
                bfr[in] = *(const bf16x8*)&Bs[(wn * 64 + in * 16 + l15) * 64 + s * 32 + quad * 8];
#pragma unroll
            for (int im = 0; im < 4; im++)
#pragma unroll
                for (int in = 0; in < 4; in++)
                    acc[im][in] = MFMA16(af[im], bfr[in], acc[im][in]);
        }
    }

    if (MODE == 0) {
        if (n0 >= 2048) {
            // ---- V block: transpose via LDS, write Vt (B,H,64,T) ----
            __syncthreads();  // main-loop LDS reads done
            bf16* const Ts = &SM[0][0];  // 128 cols x 128 rows (16384 elems)
            // write acc: phys elem = col*128 + (row ^ ((col&7)<<3))
#pragma unroll
            for (int in = 0; in < 4; in++) {
                const int col = wn * 64 + in * 16 + l15;
                const int cx = (col & 7) << 3;
#pragma unroll
                for (int im = 0; im < 4; im++) {
                    const int row0 = (wm * 64 + im * 16 + quad * 4) ^ cx;
#pragma unroll
                    for (int r = 0; r < 4; r++)
                        Ts[col * 128 + row0 + r] = (bf16)acc[im][in][r];
                }
            }
            __syncthreads();
            bf16* VtOut = O2;
            const int bb = m0 >> 11, tt0 = m0 & 2047;
            const int c0 = n0 - 2048;
#pragma unroll
            for (int p = 0; p < 8; p++) {
                const int col = p * 16 + w * 4 + (l >> 4);  // 0..127
                const int chunk = l & 15;                   // 8-row chunk
                const int physc = ((chunk ^ (col & 7)) & 7) + (chunk & 8);
                const bf16x8 v = *(const bf16x8*)&Ts[col * 128 + physc * 8];
                const int cg = c0 + col, h = cg >> 6, d = cg & 63;
                *(bf16x8*)&VtOut[((size_t)(bb * 16 + h) * 64 + d) * 2048 + tt0 + chunk * 8] = v;
            }
        } else {
            // ---- Q/K block: scatter epilogue ----
            bf16* Q0 = (bf16*)O0;
#pragma unroll
            for (int in = 0; in < 4; in++) {
                const int n = n0 + wn * 64 + in * 16;
                const int sel = n >> 10;
                const int c = n & 1023;
                const int h = c >> 6;
                const int dd = c & 63;
                bf16* dst = (sel == 0) ? Q0 : O1;
#pragma unroll
                for (int im = 0; im < 4; im++) {
#pragma unroll
                    for (int r = 0; r < 4; r++) {
                        const int m = m0 + wm * 64 + im * 16 + quad * 4 + r;
                        const int b = m >> 11, tt = m & 2047;
                        dst[((size_t)(b * 16 + h) * 2048 + tt) * 64 + dd + l15] =
                            (bf16)acc[im][in][r];
                    }
                }
            }
        }
    } else {
        float* Of = (float*)O0;
#pragma unroll
        for (int im = 0; im < 4; im++) {
#pragma unroll
            for (int in = 0; in < 4; in++) {
#pragma unroll
                for (int r = 0; r < 4; r++) {
                    const int m = m0 + wm * 64 + im * 16 + quad * 4 + r;
                    const int n = n0 + wn * 64 + in * 16 + l15;
                    Of[(size_t)m * N + n] = acc[im][in][r];
                }
            }
        }
    }
}

// ---------------------------------------------------------------------------
// Causal flash attention, merged-pair K-loop. Block owns Q-tiles qt0=pair,
// qt1=31-pair of one (b,h); ONE kt-loop 0..qt1 (half0 active while kt<=qt0).
// S computed transposed (A=K w/ permuted row map, B=Q) so each lane's S^T
// regs are exactly the PV A-frags. No-reference softmax (2^c cancels); raw
// v_exp_f32; li row-sums ride the MFMA pipe (B = ones). Q pre-scaled.
// T14 async-STAGE: next tile's K/V loads issued before compute.
// LDS layout: PLAIN ld=72 (R7's Ks read-swizzle measured WORSE: conflicts
// 6.4e6->8.0e6, +8 VGPR, +5-10us — reverted).
// Grid is (bh=64, pair=16): the 16 pair-blocks of one bh have linear ids
// congruent mod 8 -> same XCD -> K/V of that bh stays in one L2 (T1).
// ---------------------------------------------------------------------------
__launch_bounds__(256, 4)
__global__ void attn_fwd(const bf16* __restrict__ Q, const bf16* __restrict__ Kk,
                         const bf16* __restrict__ Vt, bf16* __restrict__ O) {
    __shared__ alignas(16) bf16 Ks[64 * 72];      // K tile  [kpos][d], ld=72
    __shared__ alignas(16) bf16 Vs[64 * 72];      // Vt tile [d][kpos], ld=72

    const int t = threadIdx.x, w = t >> 6, l = t & 63;
    const int quad = l >> 4, l15 = l & 15;
    const int bh = blockIdx.x, pair = blockIdx.y;   // bh fastest -> same-XCD pairs
    const int b = bh >> 4, h = bh & 15;
    const int sr = t >> 3, sc = t & 7;

    const bf16* Qbase = Q + (size_t)bh * 2048 * 64;
    const bf16* Kbase = Kk + (size_t)bh * 2048 * 64;
    const bf16* Vbase = Vt + (size_t)bh * 64 * 2048;

    const int qt0 = pair, qt1 = 31 - pair;

    // permuted K-row map: tile nt, lane-m l15 -> local K row
    int kr[4];
#pragma unroll
    for (int nt = 0; nt < 4; nt++)
        kr[nt] = (nt >> 1) * 32 + (l15 >> 2) * 8 + (nt & 1) * 4 + (l15 & 3);

    // Q B-frags for both halves, pre-scaled by log2(e)/8
    bf16x8 aq[2][2];
#pragma unroll
    for (int hf = 0; hf < 2; hf++) {
        const int qrow = (hf ? qt1 : qt0) * 64 + w * 16 + l15;
        aq[hf][0] = *(const bf16x8*)&Qbase[(size_t)qrow * 64 + quad * 8];
        aq[hf][1] = *(const bf16x8*)&Qbase[(size_t)qrow * 64 + 32 + quad * 8];
#pragma unroll
        for (int j = 0; j < 8; j++) {
            aq[hf][0][j] = aq[hf][0][j] * (bf16)0.1803369f;
            aq[hf][1][j] = aq[hf][1][j] * (bf16)0.1803369f;
        }
    }

    // ones B-frag for the li row-sum MFMA
    bf16x8 ones;
#pragma unroll
    for (int j = 0; j < 8; j++) ones[j] = (bf16)1.0f;

    f32x4 liacc[2] = {};
    f32x4 oa[2][4] = {};

    // prologue: load tile 0 into registers
    bf16x8 rk0 = *(const bf16x8*)&Kbase[(size_t)sr * 64 + sc * 8];
    bf16x8 rk1 = *(const bf16x8*)&Kbase[(size_t)(sr + 32) * 64 + sc * 8];
    bf16x8 rv0 = *(const bf16x8*)&Vbase[(size_t)sr * 2048 + sc * 8];
    bf16x8 rv1 = *(const bf16x8*)&Vbase[(size_t)(sr + 32) * 2048 + sc * 8];

    for (int kt = 0; kt <= qt1; kt++) {
        __syncthreads();  // previous iter's tile reads done
        *(bf16x8*)&Ks[sr * 72 + sc * 8] = rk0;
        *(bf16x8*)&Ks[(sr + 32) * 72 + sc * 8] = rk1;
        *(bf16x8*)&Vs[sr * 72 + sc * 8] = rv0;
        *(bf16x8*)&Vs[(sr + 32) * 72 + sc * 8] = rv1;
        __syncthreads();

        // T14: issue next tile's loads now; latency hides under compute below
        if (kt < qt1) {
            const int kn = kt + 1;
            rk0 = *(const bf16x8*)&Kbase[(size_t)(kn * 64 + sr) * 64 + sc * 8];
            rk1 = *(const bf16x8*)&Kbase[(size_t)(kn * 64 + sr + 32) * 64 + sc * 8];
            rv0 = *(const bf16x8*)&Vbase[(size_t)sr * 2048 + kn * 64 + sc * 8];
            rv1 = *(const bf16x8*)&Vbase[(size_t)(sr + 32) * 2048 + kn * 64 + sc * 8];
        }

        const bool do0 = (kt <= qt0);

        // S^T by nt-pairs; ka frags shared across halves; pack PV A-frags
        bf16x8 ap[2][2];  // [hf][s2]
#pragma unroll
        for (int np = 0; np < 2; np++) {
            bf16x8 ka[2][2];
#pragma unroll
            for (int i = 0; i < 2; i++) {
                ka[i][0] = *(const bf16x8*)&Ks[kr[2 * np + i] * 72 + quad * 8];
                ka[i][1] = *(const bf16x8*)&Ks[kr[2 * np + i] * 72 + 32 + quad * 8];
            }
#pragma unroll
            for (int hf = 0; hf < 2; hf++) {
                if (hf == 0 && !do0) continue;
                const bool diag = (kt == (hf ? qt1 : qt0));
#pragma unroll
                for (int i = 0; i < 2; i++) {
                    f32x4 s = {};
                    s = MFMA16(ka[i][0], aq[hf][0], s);
                    s = MFMA16(ka[i][1], aq[hf][1], s);
                    const int kbase = np * 32 + quad * 8 + i * 4;
#pragma unroll
                    for (int r = 0; r < 4; r++) {
                        float x = s[r];
                        if (diag && (kbase + r) > (w * 16 + l15)) x = -1e30f;
                        ap[hf][np][i * 4 + r] = (bf16)__builtin_amdgcn_exp2f(x);
                    }
                }
            }
        }

        // O += P V : bv frags read once, feed both halves.
#pragma unroll
        for (int s2 = 0; s2 < 2; s2++) {
            if (do0) liacc[0] = MFMA16(ap[0][s2], ones, liacc[0]);
            liacc[1] = MFMA16(ap[1][s2], ones, liacc[1]);
#pragma unroll
            for (int dt = 0; dt < 4; dt++) {
                bf16x8 bv = *(const bf16x8*)&Vs[(dt * 16 + l15) * 72 + s2 * 32 + quad * 8];
                if (do0) oa[0][dt] = MFMA16(ap[0][s2], bv, oa[0][dt]);
                oa[1][dt] = MFMA16(ap[1][s2], bv, oa[1][dt]);
            }
        }
    }

    // epilogue: liacc[hf][r] is already the full row-sum for q-row quad*4+r
#pragma unroll
    for (int hf = 0; hf < 2; hf++) {
        const int qt = hf ? qt1 : qt0;
#pragma unroll
        for (int r = 0; r < 4; r++) {
            const float inv = __builtin_amdgcn_rcpf(liacc[hf][r]);
            const int m = b * 2048 + qt * 64 + w * 16 + quad * 4 + r;
#pragma unroll
            for (int dt = 0; dt < 4; dt++) {
                O[(size_t)m * 1024 + h * 64 + dt * 16 + l15] = (bf16)(oa[hf][dt][r] * inv);
            }
        }
    }
}

// ---------------------------------------------------------------------------
extern "C" void kernel_launch(void* const* d_in, const int* in_sizes, int n_in,
                              void* d_out, int out_size, void* d_ws, size_t ws_size,
                              hipStream_t stream) {
    const float* x = (const float*)d_in[0];     // (8192, 1024) f32
    const float* wqkv = (const float*)d_in[1];  // (3072, 1024) f32
    const float* wo = (const float*)d_in[2];    // (1024, 1024) f32

    const size_t SZ = (size_t)8192 * 1024;
    bf16* xb = (bf16*)d_ws;                 // x bf16; reused as attn output
    bf16* wqb = xb + SZ;                    // W_qkv bf16
    bf16* wob = wqb + (size_t)3072 * 1024;  // W_o bf16
    bf16* Qw = wob + (size_t)1024 * 1024;
    bf16* Kw = Qw + SZ;
    bf16* Vtw = Kw + SZ;                    // Vt (B,H,64,T), written by gemm

    dim3 blk(256);
    cvt_all<<<6144, blk, 0, stream>>>(x, wqkv, wo, xb, wqb, wob);
    // writes Q/K scattered; V blocks write Vt directly (no vtrans kernel)
    gemm_nt<0><<<dim3(24, 64), blk, 0, stream>>>(xb, wqb, Qw, Kw, Vtw, 3072, 1024);
    // attn reads Vt, writes its output into xb (dead after the QKV gemm)
    attn_fwd<<<dim3(64, 16), blk, 0, stream>>>(Qw, Kw, Vtw, xb);
    gemm_nt<1><<<dim3(8, 64), blk, 0, stream>>>(xb, wob, d_out, nullptr, nullptr, 1024, 1024);
}